// Round 1
// baseline (5685.920 us; speedup 1.0000x reference)
//
#include <hip/hip_runtime.h>

// VQ forward on MI355X.
// x: [32768, 512] fp32, codebook: [8192, 512] fp32.
// Outputs concatenated in d_out (all read back as float32):
//   [0 .. 16777216)              quantized_st  = x + (codebook[idx] - x)   (fp32, op-replicated)
//   [16777216]                   vq_loss       = cl + 0.25f*cl, cl = mean((q-x)^2)
//   [16777217 .. 16777217+32768) indices as float32
//
// Numerics: reference computes d = fl(fl(x_sq - fl(2*dot)) + c_sq) in fp32 at
// magnitude ~512 (ulp 6.1e-5). We replicate that exact rounding chain; x_sq /
// c_sq ulp-level differences shift all d_k of a row by the same ulp multiple
// (shift-invariant rounding within a binade) so argmin is preserved. Argmin
// tie-break = lowest index via packed (fbits<<32 | idx) integer atomicMin.

#define NROWS 32768
#define KCODES 8192
#define DD 512

#define BM 64
#define BN 128
#define BK 16

// ---------------- sum of fp32 squares per row (fp64 accumulate, round to fp32)
__global__ __launch_bounds__(256) void sumsq_kernel(const float* __restrict__ in,
                                                    float* __restrict__ out,
                                                    int nrows) {
  const int wave = threadIdx.x >> 6;
  const int lane = threadIdx.x & 63;
  const int row = blockIdx.x * 4 + wave;
  if (row >= nrows) return;
  const float* p = in + (size_t)row * DD;
  double s = 0.0;
#pragma unroll
  for (int j = 0; j < DD / 64; ++j) {
    float v = p[j * 64 + lane];
    float sq = v * v;               // fp32 square first (matches ref flat*flat)
    s += (double)sq;
  }
  for (int off = 32; off > 0; off >>= 1) s += __shfl_down(s, off, 64);
  if (lane == 0) out[row] = (float)s;
}

// ---------------- main: fp32 GEMM (dot) + fused fp32-chain dist + running argmin
__global__ __launch_bounds__(256, 2) void vq_argmin_kernel(
    const float* __restrict__ x, const float* __restrict__ cb,
    const float* __restrict__ xsq, const float* __restrict__ csq,
    int* __restrict__ out_idx) {
  __shared__ float As[BK][BM];                  // 4 KB, k-major
  __shared__ float Bs[BK][BN];                  // 8 KB, k-major
  __shared__ unsigned long long best[BM];       // packed (dist_bits<<32)|idx

  const int tid = threadIdx.x;
  const int row0 = blockIdx.x * BM;

  for (int i = tid; i < BM; i += 256) best[i] = ~0ULL;

  const int ty = tid >> 4;    // 0..15 -> rows ty*4 .. ty*4+3
  const int tx = tid & 15;    // 0..15 -> codes tx*8 .. tx*8+7

  float xs_r[4];
#pragma unroll
  for (int i = 0; i < 4; ++i) xs_r[i] = xsq[row0 + ty * 4 + i];

  // staging assignments
  const int arow = tid >> 2;           // 0..63
  const int ak = (tid & 3) * 4;        // 0,4,8,12
  const int bcode = tid >> 2;          // 0..63 (and +64)
  const int bk = (tid & 3) * 4;

  __syncthreads();

  for (int ct = 0; ct < KCODES / BN; ++ct) {
    const int c0 = ct * BN;
    float acc[4][8];
#pragma unroll
    for (int i = 0; i < 4; ++i)
#pragma unroll
      for (int j = 0; j < 8; ++j) acc[i][j] = 0.0f;

    for (int kt = 0; kt < DD / BK; ++kt) {
      const int kb = kt * BK;
      __syncthreads();   // protect LDS from previous iteration's readers
      {
        float4 av = *(const float4*)(x + (size_t)(row0 + arow) * DD + kb + ak);
        As[ak + 0][arow] = av.x; As[ak + 1][arow] = av.y;
        As[ak + 2][arow] = av.z; As[ak + 3][arow] = av.w;
        float4 bv0 = *(const float4*)(cb + (size_t)(c0 + bcode) * DD + kb + bk);
        Bs[bk + 0][bcode] = bv0.x; Bs[bk + 1][bcode] = bv0.y;
        Bs[bk + 2][bcode] = bv0.z; Bs[bk + 3][bcode] = bv0.w;
        float4 bv1 = *(const float4*)(cb + (size_t)(c0 + bcode + 64) * DD + kb + bk);
        Bs[bk + 0][bcode + 64] = bv1.x; Bs[bk + 1][bcode + 64] = bv1.y;
        Bs[bk + 2][bcode + 64] = bv1.z; Bs[bk + 3][bcode + 64] = bv1.w;
      }
      __syncthreads();
#pragma unroll
      for (int kk = 0; kk < BK; ++kk) {
        float a[4], b[8];
        *(float4*)&a[0] = *(const float4*)&As[kk][ty * 4];
        *(float4*)&b[0] = *(const float4*)&Bs[kk][tx * 8];
        *(float4*)&b[4] = *(const float4*)&Bs[kk][tx * 8 + 4];
#pragma unroll
        for (int i = 0; i < 4; ++i)
#pragma unroll
          for (int j = 0; j < 8; ++j) acc[i][j] = fmaf(a[i], b[j], acc[i][j]);
      }
    }

    // per-code-tile argmin epilogue, replicating ref fp32 rounding chain
    float cs[8];
#pragma unroll
    for (int j = 0; j < 8; ++j) cs[j] = csq[c0 + tx * 8 + j];
#pragma unroll
    for (int i = 0; i < 4; ++i) {
      float bd = 3.0e38f;
      int bj = 0;
#pragma unroll
      for (int j = 0; j < 8; ++j) {
        float t = xs_r[i] - 2.0f * acc[i][j];   // 2*dot exact; one rounding
        float d = t + cs[j];                    // one rounding (magnitude ~512)
        if (d < bd) { bd = d; bj = j; }         // strict < keeps lowest j on tie
      }
      unsigned long long pk =
          ((unsigned long long)__float_as_uint(bd) << 32) |
          (unsigned)(c0 + tx * 8 + bj);
      atomicMin(&best[ty * 4 + i], pk);
    }
  }
  __syncthreads();
  for (int i = tid; i < BM; i += 256)
    out_idx[row0 + i] = (int)(best[i] & 0xffffffffu);
}

// ---------------- gather + straight-through + per-row loss partial + idx-as-float
__global__ __launch_bounds__(128) void epilogue_kernel(
    const float* __restrict__ x, const float* __restrict__ cb,
    const int* __restrict__ idx, float* __restrict__ out_q,
    float* __restrict__ out_idx_f, double* __restrict__ partials) {
  const int row = blockIdx.x;
  const int t = threadIdx.x;
  const int k = idx[row];
  const float4* xr = (const float4*)(x + (size_t)row * DD);
  const float4* qr = (const float4*)(cb + (size_t)k * DD);
  float4* orow = (float4*)(out_q + (size_t)row * DD);

  float4 xv = xr[t];
  float4 qv = qr[t];
  float dx = qv.x - xv.x, dy = qv.y - xv.y, dz = qv.z - xv.z, dw = qv.w - xv.w;
  float4 o;
  o.x = xv.x + dx; o.y = xv.y + dy; o.z = xv.z + dz; o.w = xv.w + dw;
  orow[t] = o;

  float s0 = dx * dx, s1 = dy * dy, s2 = dz * dz, s3 = dw * dw;  // fp32 squares
  double part = (double)s0 + (double)s1 + (double)s2 + (double)s3;

  for (int off = 32; off > 0; off >>= 1) part += __shfl_down(part, off, 64);
  __shared__ double red[2];
  const int lane = t & 63, wv = t >> 6;
  if (lane == 0) red[wv] = part;
  __syncthreads();
  if (t == 0) {
    partials[row] = red[0] + red[1];
    out_idx_f[row] = (float)k;
  }
}

// ---------------- reduce partials -> vq_loss
__global__ __launch_bounds__(256) void finalize_kernel(
    const double* __restrict__ partials, float* __restrict__ out_loss) {
  __shared__ double red[256];
  double s = 0.0;
  for (int i = threadIdx.x; i < NROWS; i += 256) s += partials[i];
  red[threadIdx.x] = s;
  __syncthreads();
  for (int st = 128; st > 0; st >>= 1) {
    if (threadIdx.x < st) red[threadIdx.x] += red[threadIdx.x + st];
    __syncthreads();
  }
  if (threadIdx.x == 0) {
    double mean = red[0] / ((double)NROWS * (double)DD);
    float cl = (float)mean;                // codebook_loss == commitment_loss
    out_loss[0] = cl + 0.25f * cl;         // fl(cl + fl(0.25*cl)), matches ref
  }
}

extern "C" void kernel_launch(void* const* d_in, const int* in_sizes, int n_in,
                              void* d_out, int out_size, void* d_ws,
                              size_t ws_size, hipStream_t stream) {
  const float* x = (const float*)d_in[0];
  const float* cb = (const float*)d_in[1];
  float* out = (float*)d_out;

  // ws layout (all slots fully rewritten each launch; no zero-init needed):
  char* ws = (char*)d_ws;
  double* partials = (double*)ws;                         // 32768*8  = 262144 B
  int* idxbuf = (int*)(ws + 262144);                      // 32768*4  = 131072 B
  float* csq = (float*)(ws + 262144 + 131072);            // 8192*4   =  32768 B
  float* xsq = (float*)(ws + 262144 + 131072 + 32768);    // 32768*4  = 131072 B

  sumsq_kernel<<<KCODES / 4, 256, 0, stream>>>(cb, csq, KCODES);
  sumsq_kernel<<<NROWS / 4, 256, 0, stream>>>(x, xsq, NROWS);
  vq_argmin_kernel<<<NROWS / BM, 256, 0, stream>>>(x, cb, xsq, csq, idxbuf);
  epilogue_kernel<<<NROWS, 128, 0, stream>>>(x, cb, idxbuf, out,
                                             out + 16777216 + 1, partials);
  finalize_kernel<<<1, 256, 0, stream>>>(partials, out + 16777216);
}